// Round 1
// baseline (957.936 us; speedup 1.0000x reference)
//
#include <hip/hip_runtime.h>

#define ALPHA_F 0.1f
#define EPS_F   1e-5f

// ---------------------------------------------------------------------------
// GEMM: out[M,128] = BN( act(A[M,K] @ W[K,128] + bias) )
// 128x128 tile, 256 threads, 8x8 micro-tile, K-step 16. fp32 (no fp32 MFMA).
// ---------------------------------------------------------------------------
__global__ __launch_bounds__(256) void gemm_bias_act_bn(
    const float* __restrict__ A, const float* __restrict__ W,
    const float* __restrict__ bias,
    const float* __restrict__ gamma, const float* __restrict__ beta,
    const float* __restrict__ mean,  const float* __restrict__ var,
    float* __restrict__ out, int M, int K, int do_relu)
{
    __shared__ float As[16][128];   // transposed: As[k][m]
    __shared__ float Bs[16][128];
    const int t  = threadIdx.x;
    const int bm = blockIdx.x * 128;
    const int tm = (t >> 4) << 3;   // 0..120
    const int tn = (t & 15) << 3;   // 0..120

    float acc[8][8];
#pragma unroll
    for (int i = 0; i < 8; ++i)
#pragma unroll
        for (int j = 0; j < 8; ++j) acc[i][j] = 0.f;

    for (int k0 = 0; k0 < K; k0 += 16) {
        // stage A tile (128 rows x 16 k), transposed into As[k][m]
#pragma unroll
        for (int j = 0; j < 2; ++j) {
            int idx = t * 2 + j;          // 0..511
            int row = idx >> 2;           // 0..127
            int c4  = (idx & 3) << 2;     // 0,4,8,12
            int gm  = bm + row;
            float4 v = make_float4(0.f, 0.f, 0.f, 0.f);
            if (gm < M) v = *(const float4*)&A[(size_t)gm * K + k0 + c4];
            As[c4 + 0][row] = v.x;
            As[c4 + 1][row] = v.y;
            As[c4 + 2][row] = v.z;
            As[c4 + 3][row] = v.w;
        }
        // stage W tile (16 k x 128 n)
#pragma unroll
        for (int j = 0; j < 2; ++j) {
            int idx = t * 2 + j;          // 0..511
            int row = idx >> 5;           // 0..15
            int c   = (idx & 31) << 2;    // 0..124
            *(float4*)&Bs[row][c] = *(const float4*)&W[(size_t)(k0 + row) * 128 + c];
        }
        __syncthreads();
#pragma unroll
        for (int k = 0; k < 16; ++k) {
            float a[8], b[8];
            *(float4*)&a[0] = *(const float4*)&As[k][tm];
            *(float4*)&a[4] = *(const float4*)&As[k][tm + 4];
            *(float4*)&b[0] = *(const float4*)&Bs[k][tn];
            *(float4*)&b[4] = *(const float4*)&Bs[k][tn + 4];
#pragma unroll
            for (int i = 0; i < 8; ++i)
#pragma unroll
                for (int j = 0; j < 8; ++j)
                    acc[i][j] = fmaf(a[i], b[j], acc[i][j]);
        }
        __syncthreads();
    }

    // epilogue: bias -> (relu) -> BN(eval)
    float scl[8], sft[8], bv[8];
#pragma unroll
    for (int j = 0; j < 8; ++j) {
        int n   = tn + j;
        float s = gamma[n] * rsqrtf(var[n] + EPS_F);
        scl[j]  = s;
        sft[j]  = beta[n] - mean[n] * s;
        bv[j]   = bias[n];
    }
#pragma unroll
    for (int i = 0; i < 8; ++i) {
        int gm = bm + tm + i;
        if (gm < M) {
            float vals[8];
#pragma unroll
            for (int j = 0; j < 8; ++j) {
                float v = acc[i][j] + bv[j];
                if (do_relu) v = fmaxf(v, 0.f);
                vals[j] = v * scl[j] + sft[j];
            }
            *(float4*)&out[(size_t)gm * 128 + tn]     = *(float4*)&vals[0];
            *(float4*)&out[(size_t)gm * 128 + tn + 4] = *(float4*)&vals[4];
        }
    }
}

// ---------------------------------------------------------------------------
// Graph preprocessing (once per launch)
// ---------------------------------------------------------------------------
__global__ void count_deg(const int* __restrict__ dst, int E, int* __restrict__ deg)
{
    int e = blockIdx.x * 256 + threadIdx.x;
    if (e < E) atomicAdd(&deg[dst[e]], 1);
}

__global__ __launch_bounds__(1024) void exclusive_scan_small(
    const int* __restrict__ deg, int* __restrict__ offs,
    int* __restrict__ cursor, int N)
{
    __shared__ int ssum[1024];
    const int t  = threadIdx.x;
    const int C  = (N + 1023) / 1024;
    const int lo = t * C;
    const int hi = min(lo + C, N);
    int s = 0;
    for (int i = lo; i < hi; ++i) s += deg[i];
    int val = s;
    ssum[t] = val;
    __syncthreads();
    for (int d = 1; d < 1024; d <<= 1) {
        int other = (t >= d) ? ssum[t - d] : 0;
        __syncthreads();
        val += other;
        ssum[t] = val;
        __syncthreads();
    }
    int run = val - s;  // exclusive prefix of this thread's chunk
    for (int i = lo; i < hi; ++i) {
        offs[i]   = run;
        cursor[i] = run;
        run += deg[i];
    }
}

__global__ void compute_dinv(const int* __restrict__ deg, float* __restrict__ dinv, int N)
{
    int i = blockIdx.x * 256 + threadIdx.x;
    if (i < N) dinv[i] = rsqrtf((float)(deg[i] + 1));  // +1 self loop, always >= 1
}

__global__ void scatter_csr(const int* __restrict__ src, const int* __restrict__ dst,
                            int E, const float* __restrict__ dinv,
                            int* __restrict__ cursor,
                            int* __restrict__ csr_src, float* __restrict__ csr_val)
{
    int e = blockIdx.x * 256 + threadIdx.x;
    if (e < E) {
        int s = src[e], d = dst[e];
        int pos = atomicAdd(&cursor[d], 1);
        csr_src[pos] = s;
        csr_val[pos] = dinv[s] * dinv[d];
    }
}

// ---------------------------------------------------------------------------
// One APPNP step: nxt = (1-a)*(A_hat @ cur) + a*h0
// One wave per node; 64 lanes x float2 = 128 features. CSR reads are
// wave-uniform (scalar pipe); feature gathers are 512B contiguous per edge.
// ---------------------------------------------------------------------------
__global__ __launch_bounds__(256) void appnp_step(
    const float* __restrict__ cur, const float* __restrict__ h0,
    const int* __restrict__ offs, const int* __restrict__ deg,
    const int* __restrict__ csr_src, const float* __restrict__ csr_val,
    const float* __restrict__ dinv,
    float* __restrict__ nxt, int N)
{
    int wv = (int)((blockIdx.x * 256u + threadIdx.x) >> 6);
    if (wv >= N) return;
    const int i    = __builtin_amdgcn_readfirstlane(wv);
    const int lane = (int)(threadIdx.x & 63u);
    const int c    = lane * 2;

    int e   = offs[i];
    int end = e + deg[i];
    float ax = 0.f, ay = 0.f;
    for (; e + 1 < end; e += 2) {
        int   s0 = csr_src[e];     int   s1 = csr_src[e + 1];
        float w0 = csr_val[e];     float w1 = csr_val[e + 1];
        float2 v0 = *(const float2*)&cur[(size_t)s0 * 128 + c];
        float2 v1 = *(const float2*)&cur[(size_t)s1 * 128 + c];
        ax = fmaf(w0, v0.x, ax); ay = fmaf(w0, v0.y, ay);
        ax = fmaf(w1, v1.x, ax); ay = fmaf(w1, v1.y, ay);
    }
    if (e < end) {
        int s0 = csr_src[e]; float w0 = csr_val[e];
        float2 v0 = *(const float2*)&cur[(size_t)s0 * 128 + c];
        ax = fmaf(w0, v0.x, ax); ay = fmaf(w0, v0.y, ay);
    }

    const float di = dinv[i];
    const float sl = di * di;                       // self-loop norm
    float2 sv  = *(const float2*)&cur[(size_t)i * 128 + c];
    float2 h0v = *(const float2*)&h0[(size_t)i * 128 + c];
    float2 o;
    o.x = ALPHA_F * h0v.x + (1.f - ALPHA_F) * (ax + sl * sv.x);
    o.y = ALPHA_F * h0v.y + (1.f - ALPHA_F) * (ay + sl * sv.y);
    *(float2*)&nxt[(size_t)i * 128 + c] = o;
}

// ---------------------------------------------------------------------------
static inline size_t align_up(size_t x) { return (x + 255) & ~(size_t)255; }

extern "C" void kernel_launch(void* const* d_in, const int* in_sizes, int n_in,
                              void* d_out, int out_size, void* d_ws, size_t ws_size,
                              hipStream_t stream)
{
    const float* x   = (const float*)d_in[0];
    const int*   ei  = (const int*)d_in[1];
    const float* W1  = (const float*)d_in[2];
    const float* b1  = (const float*)d_in[3];
    const float* g1  = (const float*)d_in[4];
    const float* be1 = (const float*)d_in[5];
    const float* m1  = (const float*)d_in[6];
    const float* v1  = (const float*)d_in[7];
    const float* W2  = (const float*)d_in[8];
    const float* b2  = (const float*)d_in[9];
    const float* g2  = (const float*)d_in[10];
    const float* be2 = (const float*)d_in[11];
    const float* m2  = (const float*)d_in[12];
    const float* v2  = (const float*)d_in[13];

    const int N = in_sizes[0] / 512;   // 50000
    const int E = in_sizes[1] / 2;     // 800000
    const int* src = ei;
    const int* dst = ei + E;

    char* ws = (char*)d_ws;
    size_t off = 0;
    float* h0   = (float*)(ws + off); off += align_up((size_t)N * 128 * 4);
    float* hA   = (float*)(ws + off); off += align_up((size_t)N * 128 * 4);
    int*   deg  = (int*)(ws + off);   off += align_up((size_t)N * 4);
    float* dinv = (float*)(ws + off); off += align_up((size_t)N * 4);
    int*   offs = (int*)(ws + off);   off += align_up((size_t)N * 4);
    int*   curs = (int*)(ws + off);   off += align_up((size_t)N * 4);
    int*   csrs = (int*)(ws + off);   off += align_up((size_t)E * 4);
    float* csrv = (float*)(ws + off); off += align_up((size_t)E * 4);

    // h = BN1(relu(x @ W1 + b1))    -> hA   (hA doubles as ping-pong later)
    gemm_bias_act_bn<<<(N + 127) / 128, 256, 0, stream>>>(
        x, W1, b1, g1, be1, m1, v1, hA, N, 512, 1);
    // h0 = BN2(hA @ W2 + b2)        -> h0
    gemm_bias_act_bn<<<(N + 127) / 128, 256, 0, stream>>>(
        hA, W2, b2, g2, be2, m2, v2, h0, N, 128, 0);

    // graph preprocessing (per launch; inputs static)
    hipMemsetAsync(deg, 0, (size_t)N * 4, stream);
    count_deg<<<(E + 255) / 256, 256, 0, stream>>>(dst, E, deg);
    exclusive_scan_small<<<1, 1024, 0, stream>>>(deg, offs, curs, N);
    compute_dinv<<<(N + 255) / 256, 256, 0, stream>>>(deg, dinv, N);
    scatter_csr<<<(E + 255) / 256, 256, 0, stream>>>(src, dst, E, dinv, curs, csrs, csrv);

    // 10 propagation steps; ping-pong hA <-> d_out so step 10 lands in d_out
    const float* cur = h0;
    for (int k = 0; k < 10; ++k) {
        float* nxt = (k & 1) ? (float*)d_out : hA;
        appnp_step<<<(N + 3) / 4, 256, 0, stream>>>(
            cur, h0, offs, deg, csrs, csrv, dinv, nxt, N);
        cur = nxt;
    }

    (void)n_in; (void)out_size; (void)ws_size;
}

// Round 2
// 900.878 us; speedup vs baseline: 1.0633x; 1.0633x over previous
//
#include <hip/hip_runtime.h>

#define ALPHA_F 0.1f
#define EPS_F   1e-5f

typedef __bf16 bf16_t;
typedef __bf16 bf16x8 __attribute__((ext_vector_type(8)));
typedef float  f32x4  __attribute__((ext_vector_type(4)));
typedef unsigned short u16x8 __attribute__((ext_vector_type(8)));

// ---------------------------------------------------------------------------
// W [K x 128] fp32  ->  Wt_hi/Wt_lo [128 x K] bf16 (transposed, hi/lo split)
// ---------------------------------------------------------------------------
__global__ void convert_wt(const float* __restrict__ W,
                           bf16_t* __restrict__ hi, bf16_t* __restrict__ lo, int K)
{
    int idx = blockIdx.x * 256 + threadIdx.x;
    if (idx < K * 128) {
        int k = idx >> 7, n = idx & 127;
        float f  = W[idx];
        bf16_t h = (bf16_t)f;
        hi[(size_t)n * K + k] = h;
        lo[(size_t)n * K + k] = (bf16_t)(f - (float)h);
    }
}

// ---------------------------------------------------------------------------
// out[M,128] = BN( act(A[M,K] @ W[K,128] + bias) ), MFMA bf16x3 (near-fp32).
// Block: 128 threads = 2 waves; each wave owns 32 rows (2 M-frags), N=128
// covered by 8 n-frags of mfma_f32_16x16x32_bf16. A loaded fp32 direct from
// global (rows of 128B contiguous per wave), converted in-register to hi/lo.
// W tile (128n x 32k, hi+lo) staged in LDS, rows padded to 40 -> 2-way banks.
// ---------------------------------------------------------------------------
__global__ __launch_bounds__(128) void gemm_mfma_bn(
    const float* __restrict__ A,
    const bf16_t* __restrict__ Wthi, const bf16_t* __restrict__ Wtlo,  // [128][K]
    const float* __restrict__ bias,
    const float* __restrict__ gamma, const float* __restrict__ beta,
    const float* __restrict__ mean,  const float* __restrict__ var,
    float* __restrict__ out, int M, int K, int do_relu)
{
    __shared__ __align__(16) unsigned short WH[128][40];
    __shared__ __align__(16) unsigned short WL[128][40];

    const int t   = threadIdx.x;       // 0..127
    const int w   = t >> 6;            // wave 0..1
    const int l   = t & 63;
    const int l15 = l & 15;
    const int lk  = l >> 4;            // k-group 0..3
    const int bm  = blockIdx.x * 64;

    f32x4 acc[2][8];
#pragma unroll
    for (int m = 0; m < 2; ++m)
#pragma unroll
        for (int f = 0; f < 8; ++f) acc[m][f] = (f32x4){0.f, 0.f, 0.f, 0.f};

    for (int k0 = 0; k0 < K; k0 += 32) {
        // --- issue A loads (fp32, 8 k-elems per lane per m-frag) ---
        f32x4 x0[2], x1[2];
#pragma unroll
        for (int m = 0; m < 2; ++m) {
            int r = bm + w * 32 + m * 16 + l15;
            x0[m] = (f32x4){0.f, 0.f, 0.f, 0.f};
            x1[m] = x0[m];
            if (r < M) {
                const float* ap = A + (size_t)r * K + k0 + lk * 8;
                x0[m] = *(const f32x4*)ap;
                x1[m] = *(const f32x4*)(ap + 4);
            }
        }
        // --- stage W tile into LDS: thread t handles row n=t ---
        {
            const bf16_t* gh = Wthi + (size_t)t * K + k0;
            const bf16_t* gl = Wtlo + (size_t)t * K + k0;
#pragma unroll
            for (int c = 0; c < 4; ++c) {
                *(u16x8*)&WH[t][c * 8] = *(const u16x8*)(gh + c * 8);
                *(u16x8*)&WL[t][c * 8] = *(const u16x8*)(gl + c * 8);
            }
        }
        __syncthreads();

        // --- convert A to hi/lo bf16 fragments ---
        bf16x8 ahi[2], alo[2];
#pragma unroll
        for (int m = 0; m < 2; ++m) {
#pragma unroll
            for (int j = 0; j < 4; ++j) {
                float f0 = x0[m][j];
                bf16_t h0 = (bf16_t)f0;
                ahi[m][j] = h0;
                alo[m][j] = (bf16_t)(f0 - (float)h0);
                float f1 = x1[m][j];
                bf16_t h1 = (bf16_t)f1;
                ahi[m][4 + j] = h1;
                alo[m][4 + j] = (bf16_t)(f1 - (float)h1);
            }
        }
        // --- MFMA: 8 n-frags x 2 m-frags x 3 products ---
#pragma unroll
        for (int f = 0; f < 8; ++f) {
            u16x8 uh = *(const u16x8*)&WH[f * 16 + l15][lk * 8];
            u16x8 ul = *(const u16x8*)&WL[f * 16 + l15][lk * 8];
            bf16x8 wh = __builtin_bit_cast(bf16x8, uh);
            bf16x8 wl = __builtin_bit_cast(bf16x8, ul);
#pragma unroll
            for (int m = 0; m < 2; ++m) {
                acc[m][f] = __builtin_amdgcn_mfma_f32_16x16x32_bf16(ahi[m], wh, acc[m][f], 0, 0, 0);
                acc[m][f] = __builtin_amdgcn_mfma_f32_16x16x32_bf16(alo[m], wh, acc[m][f], 0, 0, 0);
                acc[m][f] = __builtin_amdgcn_mfma_f32_16x16x32_bf16(ahi[m], wl, acc[m][f], 0, 0, 0);
            }
        }
        __syncthreads();
    }

    // --- epilogue: bias -> (relu) -> BN(eval). D: col=l&15, row=(l>>4)*4+r ---
#pragma unroll
    for (int f = 0; f < 8; ++f) {
        int col  = f * 16 + l15;
        float s  = gamma[col] * rsqrtf(var[col] + EPS_F);
        float sh = beta[col] - mean[col] * s;
        float bb = bias[col];
#pragma unroll
        for (int m = 0; m < 2; ++m) {
            int rbase = bm + w * 32 + m * 16 + lk * 4;
#pragma unroll
            for (int rr = 0; rr < 4; ++rr) {
                int rg = rbase + rr;
                if (rg < M) {
                    float v = acc[m][f][rr] + bb;
                    if (do_relu) v = fmaxf(v, 0.f);
                    out[(size_t)rg * 128 + col] = v * s + sh;
                }
            }
        }
    }
}

// ---------------------------------------------------------------------------
// Graph preprocessing (per launch)
// ---------------------------------------------------------------------------
__global__ void count_deg(const int* __restrict__ dst, int E, int* __restrict__ deg)
{
    int e = blockIdx.x * 256 + threadIdx.x;
    if (e < E) atomicAdd(&deg[dst[e]], 1);
}

// padded count per node: self-loop + edges, rounded up to multiple of 4
__device__ __forceinline__ int pad_cnt(int d) { return (d + 4) & ~3; }

__global__ __launch_bounds__(1024) void exclusive_scan_small(
    const int* __restrict__ deg, int* __restrict__ offs,
    int* __restrict__ cursor, int N)
{
    __shared__ int ssum[1024];
    const int t  = threadIdx.x;
    const int C  = (N + 1023) / 1024;
    const int lo = t * C;
    const int hi = min(lo + C, N);
    int s = 0;
    for (int i = lo; i < hi; ++i) s += pad_cnt(deg[i]);
    int val = s;
    ssum[t] = val;
    __syncthreads();
    for (int d = 1; d < 1024; d <<= 1) {
        int other = (t >= d) ? ssum[t - d] : 0;
        __syncthreads();
        val += other;
        ssum[t] = val;
        __syncthreads();
    }
    int run = val - s;
    for (int i = lo; i < hi; ++i) {
        offs[i]   = run;
        cursor[i] = run;
        run += pad_cnt(deg[i]);
    }
    if (t == 1023) offs[N] = ssum[1023];
}

__global__ void compute_dinv(const int* __restrict__ deg, float* __restrict__ dinv, int N)
{
    int i = blockIdx.x * 256 + threadIdx.x;
    if (i < N) dinv[i] = rsqrtf((float)(deg[i] + 1));  // +1 self loop
}

__global__ void scatter_csr(const int* __restrict__ src, const int* __restrict__ dst,
                            int E, const float* __restrict__ dinv,
                            int* __restrict__ cursor,
                            int* __restrict__ csr_src, float* __restrict__ csr_val)
{
    int e = blockIdx.x * 256 + threadIdx.x;
    if (e < E) {
        int s = src[e], d = dst[e];
        int pos = atomicAdd(&cursor[d], 1);
        csr_src[pos] = s;
        csr_val[pos] = dinv[s] * dinv[d];
    }
}

// self-loop entry + zero-weight pads to fill each node's segment to offs[i+1]
__global__ void fill_self_pad(const int* __restrict__ offs, const int* __restrict__ deg,
                              const float* __restrict__ dinv,
                              int* __restrict__ csr_src, float* __restrict__ csr_val, int N)
{
    int i = blockIdx.x * 256 + threadIdx.x;
    if (i < N) {
        int base = offs[i], d = deg[i], end = offs[i + 1];
        float di = dinv[i];
        csr_src[base + d] = i;
        csr_val[base + d] = di * di;
        for (int p = base + d + 1; p < end; ++p) {
            csr_src[p] = i;
            csr_val[p] = 0.f;
        }
    }
}

// ---------------------------------------------------------------------------
// One APPNP step: nxt = (1-a)*(A_hat @ cur) + a*h0.  One wave per node,
// 64 lanes x float2 = 128 feats. Segments padded to x4 -> tail-free unroll-4,
// one s_load_dwordx4 of csr_src + one of csr_val per 4 edges, 4 gathers in
// flight. Self-loop folded into CSR.
// ---------------------------------------------------------------------------
__global__ __launch_bounds__(256) void appnp_step(
    const float* __restrict__ cur, const float* __restrict__ h0,
    const int* __restrict__ offs,
    const int* __restrict__ csr_src, const float* __restrict__ csr_val,
    float* __restrict__ nxt, int N)
{
    int wv = (int)((blockIdx.x * 256u + threadIdx.x) >> 6);
    if (wv >= N) return;
    const int i    = __builtin_amdgcn_readfirstlane(wv);
    const int lane = (int)(threadIdx.x & 63u);
    const int c    = lane * 2;

    int e   = offs[i];
    int end = offs[i + 1];
    float ax = 0.f, ay = 0.f;
    for (; e < end; e += 4) {
        int4   s4 = *(const int4*)(csr_src + e);
        float4 w4 = *(const float4*)(csr_val + e);
        float2 v0 = *(const float2*)(cur + (size_t)s4.x * 128 + c);
        float2 v1 = *(const float2*)(cur + (size_t)s4.y * 128 + c);
        float2 v2 = *(const float2*)(cur + (size_t)s4.z * 128 + c);
        float2 v3 = *(const float2*)(cur + (size_t)s4.w * 128 + c);
        ax = fmaf(w4.x, v0.x, ax); ay = fmaf(w4.x, v0.y, ay);
        ax = fmaf(w4.y, v1.x, ax); ay = fmaf(w4.y, v1.y, ay);
        ax = fmaf(w4.z, v2.x, ax); ay = fmaf(w4.z, v2.y, ay);
        ax = fmaf(w4.w, v3.x, ax); ay = fmaf(w4.w, v3.y, ay);
    }

    float2 h0v = *(const float2*)(h0 + (size_t)i * 128 + c);
    float2 o;
    o.x = ALPHA_F * h0v.x + (1.f - ALPHA_F) * ax;
    o.y = ALPHA_F * h0v.y + (1.f - ALPHA_F) * ay;
    *(float2*)(nxt + (size_t)i * 128 + c) = o;
}

// ---------------------------------------------------------------------------
static inline size_t align_up(size_t x) { return (x + 255) & ~(size_t)255; }

extern "C" void kernel_launch(void* const* d_in, const int* in_sizes, int n_in,
                              void* d_out, int out_size, void* d_ws, size_t ws_size,
                              hipStream_t stream)
{
    const float* x   = (const float*)d_in[0];
    const int*   ei  = (const int*)d_in[1];
    const float* W1  = (const float*)d_in[2];
    const float* b1  = (const float*)d_in[3];
    const float* g1  = (const float*)d_in[4];
    const float* be1 = (const float*)d_in[5];
    const float* m1  = (const float*)d_in[6];
    const float* v1  = (const float*)d_in[7];
    const float* W2  = (const float*)d_in[8];
    const float* b2  = (const float*)d_in[9];
    const float* g2  = (const float*)d_in[10];
    const float* be2 = (const float*)d_in[11];
    const float* m2  = (const float*)d_in[12];
    const float* v2  = (const float*)d_in[13];

    const int N = in_sizes[0] / 512;   // 50000
    const int E = in_sizes[1] / 2;     // 800000
    const int* src = ei;
    const int* dst = ei + E;
    const int CSR_CAP = E + 4 * N;

    char* ws = (char*)d_ws;
    size_t off = 0;
    float*  h0   = (float*)(ws + off);  off += align_up((size_t)N * 128 * 4);
    float*  hA   = (float*)(ws + off);  off += align_up((size_t)N * 128 * 4);
    int*    deg  = (int*)(ws + off);    off += align_up((size_t)N * 4);
    float*  dinv = (float*)(ws + off);  off += align_up((size_t)N * 4);
    int*    offs = (int*)(ws + off);    off += align_up((size_t)(N + 1) * 4);
    int*    curs = (int*)(ws + off);    off += align_up((size_t)N * 4);
    int*    csrs = (int*)(ws + off);    off += align_up((size_t)CSR_CAP * 4);
    float*  csrv = (float*)(ws + off);  off += align_up((size_t)CSR_CAP * 4);
    bf16_t* w1h  = (bf16_t*)(ws + off); off += align_up((size_t)512 * 128 * 2);
    bf16_t* w1l  = (bf16_t*)(ws + off); off += align_up((size_t)512 * 128 * 2);
    bf16_t* w2h  = (bf16_t*)(ws + off); off += align_up((size_t)128 * 128 * 2);
    bf16_t* w2l  = (bf16_t*)(ws + off); off += align_up((size_t)128 * 128 * 2);

    // --- graph preprocessing ---
    hipMemsetAsync(deg, 0, (size_t)N * 4, stream);
    count_deg<<<(E + 255) / 256, 256, 0, stream>>>(dst, E, deg);
    exclusive_scan_small<<<1, 1024, 0, stream>>>(deg, offs, curs, N);
    compute_dinv<<<(N + 255) / 256, 256, 0, stream>>>(deg, dinv, N);
    scatter_csr<<<(E + 255) / 256, 256, 0, stream>>>(src, dst, E, dinv, curs, csrs, csrv);
    fill_self_pad<<<(N + 255) / 256, 256, 0, stream>>>(offs, deg, dinv, csrs, csrv, N);

    // --- weights -> transposed bf16 hi/lo ---
    convert_wt<<<(512 * 128 + 255) / 256, 256, 0, stream>>>(W1, w1h, w1l, 512);
    convert_wt<<<(128 * 128 + 255) / 256, 256, 0, stream>>>(W2, w2h, w2l, 128);

    // --- MLP: hA = BN1(relu(x@W1+b1)); h0 = BN2(hA@W2+b2) ---
    gemm_mfma_bn<<<(N + 63) / 64, 128, 0, stream>>>(
        x, w1h, w1l, b1, g1, be1, m1, v1, hA, N, 512, 1);
    gemm_mfma_bn<<<(N + 63) / 64, 128, 0, stream>>>(
        hA, w2h, w2l, b2, g2, be2, m2, v2, h0, N, 128, 0);

    // --- 10 propagation steps; step 10 lands in d_out ---
    const float* cur = h0;
    for (int k = 0; k < 10; ++k) {
        float* nxt = (k & 1) ? (float*)d_out : hA;
        appnp_step<<<(N + 3) / 4, 256, 0, stream>>>(
            cur, h0, offs, csrs, csrv, nxt, N);
        cur = nxt;
    }

    (void)n_in; (void)out_size; (void)ws_size;
}

// Round 3
// 798.754 us; speedup vs baseline: 1.1993x; 1.1279x over previous
//
#include <hip/hip_runtime.h>

#define ALPHA_F 0.1f
#define EPS_F   1e-5f

typedef __bf16 bf16_t;
typedef __bf16 bf16x8 __attribute__((ext_vector_type(8)));
typedef float  f32x4  __attribute__((ext_vector_type(4)));
typedef unsigned short u16x8 __attribute__((ext_vector_type(8)));

// padded count per node: self-loop + edges, rounded up to multiple of 8
__device__ __forceinline__ int pad_cnt(int d) { return (d + 8) & ~7; }

// ---------------------------------------------------------------------------
// W [K x 128] fp32  ->  Wt_hi/Wt_lo [128 x K] bf16 (transposed, hi/lo split)
// ---------------------------------------------------------------------------
__global__ void convert_wt(const float* __restrict__ W,
                           bf16_t* __restrict__ hi, bf16_t* __restrict__ lo, int K)
{
    int idx = blockIdx.x * 256 + threadIdx.x;
    if (idx < K * 128) {
        int k = idx >> 7, n = idx & 127;
        float f  = W[idx];
        bf16_t h = (bf16_t)f;
        hi[(size_t)n * K + k] = h;
        lo[(size_t)n * K + k] = (bf16_t)(f - (float)h);
    }
}

// ---------------------------------------------------------------------------
// out[M,128] = BN( act(A[M,K] @ W[K,128] + bias) ), MFMA bf16x3 (near-fp32).
// ---------------------------------------------------------------------------
__global__ __launch_bounds__(128) void gemm_mfma_bn(
    const float* __restrict__ A,
    const bf16_t* __restrict__ Wthi, const bf16_t* __restrict__ Wtlo,  // [128][K]
    const float* __restrict__ bias,
    const float* __restrict__ gamma, const float* __restrict__ beta,
    const float* __restrict__ mean,  const float* __restrict__ var,
    float* __restrict__ out, int M, int K, int do_relu)
{
    __shared__ __align__(16) unsigned short WH[128][40];
    __shared__ __align__(16) unsigned short WL[128][40];

    const int t   = threadIdx.x;       // 0..127
    const int w   = t >> 6;            // wave 0..1
    const int l   = t & 63;
    const int l15 = l & 15;
    const int lk  = l >> 4;            // k-group 0..3
    const int bm  = blockIdx.x * 64;

    f32x4 acc[2][8];
#pragma unroll
    for (int m = 0; m < 2; ++m)
#pragma unroll
        for (int f = 0; f < 8; ++f) acc[m][f] = (f32x4){0.f, 0.f, 0.f, 0.f};

    for (int k0 = 0; k0 < K; k0 += 32) {
        f32x4 x0[2], x1[2];
#pragma unroll
        for (int m = 0; m < 2; ++m) {
            int r = bm + w * 32 + m * 16 + l15;
            x0[m] = (f32x4){0.f, 0.f, 0.f, 0.f};
            x1[m] = x0[m];
            if (r < M) {
                const float* ap = A + (size_t)r * K + k0 + lk * 8;
                x0[m] = *(const f32x4*)ap;
                x1[m] = *(const f32x4*)(ap + 4);
            }
        }
        {
            const bf16_t* gh = Wthi + (size_t)t * K + k0;
            const bf16_t* gl = Wtlo + (size_t)t * K + k0;
#pragma unroll
            for (int c = 0; c < 4; ++c) {
                *(u16x8*)&WH[t][c * 8] = *(const u16x8*)(gh + c * 8);
                *(u16x8*)&WL[t][c * 8] = *(const u16x8*)(gl + c * 8);
            }
        }
        __syncthreads();

        bf16x8 ahi[2], alo[2];
#pragma unroll
        for (int m = 0; m < 2; ++m) {
#pragma unroll
            for (int j = 0; j < 4; ++j) {
                float f0 = x0[m][j];
                bf16_t h0 = (bf16_t)f0;
                ahi[m][j] = h0;
                alo[m][j] = (bf16_t)(f0 - (float)h0);
                float f1 = x1[m][j];
                bf16_t h1 = (bf16_t)f1;
                ahi[m][4 + j] = h1;
                alo[m][4 + j] = (bf16_t)(f1 - (float)h1);
            }
        }
#pragma unroll
        for (int f = 0; f < 8; ++f) {
            u16x8 uh = *(const u16x8*)&WH[f * 16 + l15][lk * 8];
            u16x8 ul = *(const u16x8*)&WL[f * 16 + l15][lk * 8];
            bf16x8 wh = __builtin_bit_cast(bf16x8, uh);
            bf16x8 wl = __builtin_bit_cast(bf16x8, ul);
#pragma unroll
            for (int m = 0; m < 2; ++m) {
                acc[m][f] = __builtin_amdgcn_mfma_f32_16x16x32_bf16(ahi[m], wh, acc[m][f], 0, 0, 0);
                acc[m][f] = __builtin_amdgcn_mfma_f32_16x16x32_bf16(alo[m], wh, acc[m][f], 0, 0, 0);
                acc[m][f] = __builtin_amdgcn_mfma_f32_16x16x32_bf16(ahi[m], wl, acc[m][f], 0, 0, 0);
            }
        }
        __syncthreads();
    }

#pragma unroll
    for (int f = 0; f < 8; ++f) {
        int col  = f * 16 + l15;
        float s  = gamma[col] * rsqrtf(var[col] + EPS_F);
        float sh = beta[col] - mean[col] * s;
        float bb = bias[col];
#pragma unroll
        for (int m = 0; m < 2; ++m) {
            int rbase = bm + w * 32 + m * 16 + lk * 4;
#pragma unroll
            for (int rr = 0; rr < 4; ++rr) {
                int rg = rbase + rr;
                if (rg < M) {
                    float v = acc[m][f][rr] + bb;
                    if (do_relu) v = fmaxf(v, 0.f);
                    out[(size_t)rg * 128 + col] = v * s + sh;
                }
            }
        }
    }
}

// ---------------------------------------------------------------------------
// Graph preprocessing (per launch)
// ---------------------------------------------------------------------------
__global__ void count_deg(const int* __restrict__ dst, int E, int* __restrict__ deg)
{
    int e = blockIdx.x * 256 + threadIdx.x;
    if (e < E) atomicAdd(&deg[dst[e]], 1);
}

// k1: per-block (1024 nodes) sum of padded counts
__global__ __launch_bounds__(256) void scan_block_sums(
    const int* __restrict__ deg, int* __restrict__ bsum, int N)
{
    __shared__ int sh[256];
    const int t  = threadIdx.x;
    const int i0 = blockIdx.x * 1024 + t * 4;
    int s = 0;
    if (i0 + 3 < N) {
        int4 d4 = *(const int4*)(deg + i0);
        s = pad_cnt(d4.x) + pad_cnt(d4.y) + pad_cnt(d4.z) + pad_cnt(d4.w);
    } else {
#pragma unroll
        for (int j = 0; j < 4; ++j)
            if (i0 + j < N) s += pad_cnt(deg[i0 + j]);
    }
    sh[t] = s;
    __syncthreads();
#pragma unroll
    for (int d = 128; d > 0; d >>= 1) {
        if (t < d) sh[t] += sh[t + d];
        __syncthreads();
    }
    if (t == 0) bsum[blockIdx.x] = sh[0];
}

// k2: per-block base (reduce of prior bsum) + local Hillis-Steele -> offs/cursor
__global__ __launch_bounds__(256) void scan_offsets(
    const int* __restrict__ deg, const int* __restrict__ bsum,
    int* __restrict__ offs, int* __restrict__ cursor, int N, int B)
{
    __shared__ int sh[256];
    __shared__ int sbase;
    const int b = blockIdx.x, t = threadIdx.x;

    int v = (t < b && t < B) ? bsum[t] : 0;   // B <= 256
    sh[t] = v;
    __syncthreads();
#pragma unroll
    for (int d = 128; d > 0; d >>= 1) {
        if (t < d) sh[t] += sh[t + d];
        __syncthreads();
    }
    if (t == 0) sbase = sh[0];
    __syncthreads();

    const int i0 = b * 1024 + t * 4;
    int c[4], s = 0;
#pragma unroll
    for (int j = 0; j < 4; ++j) {
        int i = i0 + j;
        c[j] = (i < N) ? pad_cnt(deg[i]) : 0;
        s += c[j];
    }
    sh[t] = s;
    __syncthreads();
    for (int d = 1; d < 256; d <<= 1) {
        int o = (t >= d) ? sh[t - d] : 0;
        __syncthreads();
        sh[t] += o;
        __syncthreads();
    }
    int run = sbase + sh[t] - s;   // exclusive prefix
#pragma unroll
    for (int j = 0; j < 4; ++j) {
        int i = i0 + j;
        if (i < N) {
            offs[i]   = run;
            cursor[i] = run;
            run += c[j];
        }
    }
    if (b == B - 1 && t == 255) offs[N] = run;
}

__global__ void compute_dinv(const int* __restrict__ deg, float* __restrict__ dinv, int N)
{
    int i = blockIdx.x * 256 + threadIdx.x;
    if (i < N) dinv[i] = rsqrtf((float)(deg[i] + 1));  // +1 self loop
}

__global__ void scatter_csr(const int* __restrict__ src, const int* __restrict__ dst,
                            int E, const float* __restrict__ dinv,
                            int* __restrict__ cursor,
                            int* __restrict__ csr_src, float* __restrict__ csr_val)
{
    int e = blockIdx.x * 256 + threadIdx.x;
    if (e < E) {
        int s = src[e], d = dst[e];
        int pos = atomicAdd(&cursor[d], 1);
        csr_src[pos] = s;
        csr_val[pos] = dinv[s] * dinv[d];
    }
}

__global__ void fill_self_pad(const int* __restrict__ offs, const int* __restrict__ deg,
                              const float* __restrict__ dinv,
                              int* __restrict__ csr_src, float* __restrict__ csr_val, int N)
{
    int i = blockIdx.x * 256 + threadIdx.x;
    if (i < N) {
        int base = offs[i], d = deg[i], end = offs[i + 1];
        float di = dinv[i];
        csr_src[base + d] = i;
        csr_val[base + d] = di * di;
        for (int p = base + d + 1; p < end; ++p) {
            csr_src[p] = i;
            csr_val[p] = 0.f;
        }
    }
}

// ---------------------------------------------------------------------------
// One APPNP step: nxt = (1-a)*(A_hat @ cur) + a*h0.  One wave per node,
// 64 lanes x float2 = 128 feats. Segments padded to x8 -> tail-free unroll-8,
// 8 gathers in flight per wave. CSR metadata via scalar loads (uniform addr).
// ---------------------------------------------------------------------------
__global__ __launch_bounds__(256) void appnp_step(
    const float* __restrict__ cur, const float* __restrict__ h0,
    const int* __restrict__ offs,
    const int* __restrict__ csr_src, const float* __restrict__ csr_val,
    float* __restrict__ nxt, int N)
{
    int wv = (int)((blockIdx.x * 256u + threadIdx.x) >> 6);
    if (wv >= N) return;
    const int i    = __builtin_amdgcn_readfirstlane(wv);
    const int lane = (int)(threadIdx.x & 63u);
    const int c    = lane * 2;

    int e   = offs[i];
    int end = offs[i + 1];
    float ax = 0.f, ay = 0.f;
    for (; e < end; e += 8) {
        int4   sa = *(const int4*)(csr_src + e);
        int4   sb = *(const int4*)(csr_src + e + 4);
        float4 wa = *(const float4*)(csr_val + e);
        float4 wb = *(const float4*)(csr_val + e + 4);
        float2 v0 = *(const float2*)(cur + (size_t)sa.x * 128 + c);
        float2 v1 = *(const float2*)(cur + (size_t)sa.y * 128 + c);
        float2 v2 = *(const float2*)(cur + (size_t)sa.z * 128 + c);
        float2 v3 = *(const float2*)(cur + (size_t)sa.w * 128 + c);
        float2 v4 = *(const float2*)(cur + (size_t)sb.x * 128 + c);
        float2 v5 = *(const float2*)(cur + (size_t)sb.y * 128 + c);
        float2 v6 = *(const float2*)(cur + (size_t)sb.z * 128 + c);
        float2 v7 = *(const float2*)(cur + (size_t)sb.w * 128 + c);
        ax = fmaf(wa.x, v0.x, ax); ay = fmaf(wa.x, v0.y, ay);
        ax = fmaf(wa.y, v1.x, ax); ay = fmaf(wa.y, v1.y, ay);
        ax = fmaf(wa.z, v2.x, ax); ay = fmaf(wa.z, v2.y, ay);
        ax = fmaf(wa.w, v3.x, ax); ay = fmaf(wa.w, v3.y, ay);
        ax = fmaf(wb.x, v4.x, ax); ay = fmaf(wb.x, v4.y, ay);
        ax = fmaf(wb.y, v5.x, ax); ay = fmaf(wb.y, v5.y, ay);
        ax = fmaf(wb.z, v6.x, ax); ay = fmaf(wb.z, v6.y, ay);
        ax = fmaf(wb.w, v7.x, ax); ay = fmaf(wb.w, v7.y, ay);
    }

    float2 h0v = *(const float2*)(h0 + (size_t)i * 128 + c);
    float2 o;
    o.x = ALPHA_F * h0v.x + (1.f - ALPHA_F) * ax;
    o.y = ALPHA_F * h0v.y + (1.f - ALPHA_F) * ay;
    *(float2*)(nxt + (size_t)i * 128 + c) = o;
}

// ---------------------------------------------------------------------------
static inline size_t align_up(size_t x) { return (x + 255) & ~(size_t)255; }

extern "C" void kernel_launch(void* const* d_in, const int* in_sizes, int n_in,
                              void* d_out, int out_size, void* d_ws, size_t ws_size,
                              hipStream_t stream)
{
    const float* x   = (const float*)d_in[0];
    const int*   ei  = (const int*)d_in[1];
    const float* W1  = (const float*)d_in[2];
    const float* b1  = (const float*)d_in[3];
    const float* g1  = (const float*)d_in[4];
    const float* be1 = (const float*)d_in[5];
    const float* m1  = (const float*)d_in[6];
    const float* v1  = (const float*)d_in[7];
    const float* W2  = (const float*)d_in[8];
    const float* b2  = (const float*)d_in[9];
    const float* g2  = (const float*)d_in[10];
    const float* be2 = (const float*)d_in[11];
    const float* m2  = (const float*)d_in[12];
    const float* v2  = (const float*)d_in[13];

    const int N = in_sizes[0] / 512;   // 50000
    const int E = in_sizes[1] / 2;     // 800000
    const int* src = ei;
    const int* dst = ei + E;
    const int CSR_CAP = E + 8 * N;
    const int NB = (N + 1023) / 1024;  // scan blocks (49)

    char* ws = (char*)d_ws;
    size_t off = 0;
    float*  h0   = (float*)(ws + off);  off += align_up((size_t)N * 128 * 4);
    float*  hA   = (float*)(ws + off);  off += align_up((size_t)N * 128 * 4);
    int*    deg  = (int*)(ws + off);    off += align_up((size_t)N * 4);
    float*  dinv = (float*)(ws + off);  off += align_up((size_t)N * 4);
    int*    offs = (int*)(ws + off);    off += align_up((size_t)(N + 1) * 4);
    int*    curs = (int*)(ws + off);    off += align_up((size_t)N * 4);
    int*    bsum = (int*)(ws + off);    off += align_up((size_t)256 * 4);
    int*    csrs = (int*)(ws + off);    off += align_up((size_t)CSR_CAP * 4);
    float*  csrv = (float*)(ws + off);  off += align_up((size_t)CSR_CAP * 4);
    bf16_t* w1h  = (bf16_t*)(ws + off); off += align_up((size_t)512 * 128 * 2);
    bf16_t* w1l  = (bf16_t*)(ws + off); off += align_up((size_t)512 * 128 * 2);
    bf16_t* w2h  = (bf16_t*)(ws + off); off += align_up((size_t)128 * 128 * 2);
    bf16_t* w2l  = (bf16_t*)(ws + off); off += align_up((size_t)128 * 128 * 2);

    // --- graph preprocessing ---
    hipMemsetAsync(deg, 0, (size_t)N * 4, stream);
    count_deg<<<(E + 255) / 256, 256, 0, stream>>>(dst, E, deg);
    scan_block_sums<<<NB, 256, 0, stream>>>(deg, bsum, N);
    scan_offsets<<<NB, 256, 0, stream>>>(deg, bsum, offs, curs, N, NB);
    compute_dinv<<<(N + 255) / 256, 256, 0, stream>>>(deg, dinv, N);
    scatter_csr<<<(E + 255) / 256, 256, 0, stream>>>(src, dst, E, dinv, curs, csrs, csrv);
    fill_self_pad<<<(N + 255) / 256, 256, 0, stream>>>(offs, deg, dinv, csrs, csrv, N);

    // --- weights -> transposed bf16 hi/lo ---
    convert_wt<<<(512 * 128 + 255) / 256, 256, 0, stream>>>(W1, w1h, w1l, 512);
    convert_wt<<<(128 * 128 + 255) / 256, 256, 0, stream>>>(W2, w2h, w2l, 128);

    // --- MLP: hA = BN1(relu(x@W1+b1)); h0 = BN2(hA@W2+b2) ---
    gemm_mfma_bn<<<(N + 63) / 64, 128, 0, stream>>>(
        x, w1h, w1l, b1, g1, be1, m1, v1, hA, N, 512, 1);
    gemm_mfma_bn<<<(N + 63) / 64, 128, 0, stream>>>(
        hA, w2h, w2l, b2, g2, be2, m2, v2, h0, N, 128, 0);

    // --- 10 propagation steps; step 10 lands in d_out ---
    const float* cur = h0;
    for (int k = 0; k < 10; ++k) {
        float* nxt = (k & 1) ? (float*)d_out : hA;
        appnp_step<<<(N + 3) / 4, 256, 0, stream>>>(
            cur, h0, offs, csrs, csrv, nxt, N);
        cur = nxt;
    }

    (void)n_in; (void)out_size; (void)ws_size;
}